// Round 12
// baseline (79.501 us; speedup 1.0000x reference)
//
#include <hip/hip_runtime.h>
#include <math.h>

// ===== R6 (27.8 us) kernels, byte-identical; ablation: part1 x4 + merge x1 =====

#define N1V    8192
#define N2V    8192
#define BLOCK  1024               // 16 waves
#define NW     16
#define NOCT   8                  // N1 split into eighths across blockIdx.y
#define OCT    (N1V / NOCT)       // 1024 points staged per block
#define TILES  (OCT / 16)         // 64 MFMA tiles per scan
#define QPW    16                 // queries per wave (MFMA N dim)
#define QPB    (NW * QPW)         // 256 queries per block
#define TKEYMASK 0xFFFFFFC0u      // tile key: low 6 bits = tile id
#define TMASK    0x3Fu
#define PKEYMASK 0xFFFFFC00u      // point key: low 10 bits = local point idx
#define PMASK    0x3FFu
#define FMAXV  __uint_as_float(0x7F7FFFFFu)

typedef __attribute__((ext_vector_type(8))) short short8;
typedef __attribute__((ext_vector_type(4))) float float4v;

__device__ __forceinline__ void bsplit(float x, unsigned short& h, unsigned short& l) {
    unsigned hb = __float_as_uint(x) & 0xFFFF0000u;
    h = (unsigned short)(hb >> 16);
    float lo = x - __uint_as_float(hb);
    l = (unsigned short)(__float_as_uint(lo) >> 16);
}

__global__ __launch_bounds__(BLOCK, 8)
void knn_part(const float* __restrict__ xyz1,
              const float* __restrict__ xyz2,
              const float* __restrict__ flow1,
              float2* __restrict__ ws)
{
    __shared__ __align__(16) unsigned short sA[TILES * 256]; // 32 KB bf16 A-frags
    __shared__ float4 sPts[OCT];                             // 16 KB exact points
    __shared__ float  sCand[NW][64 * 3];                     // 12 KB packed top-3

    const int b     = blockIdx.z;
    const int oc    = blockIdx.y;
    const int qbase = blockIdx.x * QPB;
    const int t     = threadIdx.x;
    const int lane  = t & 63;
    const int w     = t >> 6;

    const float* x1 = xyz1 + b * 3 * N1V + oc * OCT;
    const float* f1 = flow1 + b * 3 * N1V + oc * OCT;
    const float* x2 = xyz2 + b * 3 * N2V;

    {
        const int j = t;
        float sx = x1[j]           + f1[j];
        float sy = x1[N1V + j]     + f1[N1V + j];
        float sz = x1[2*N1V + j]   + f1[2*N1V + j];
        float wv = fmaf(sx, sx, fmaf(sy, sy, sz * sz));
        sPts[j] = make_float4(sx, sy, sz, wv);
        unsigned short xh,xl,yh,yl,zh,zl,wh,wl;
        bsplit(sx, xh, xl); bsplit(sy, yh, yl);
        bsplit(sz, zh, zl); bsplit(wv, wh, wl);
        unsigned base = (unsigned)(j >> 4) * 256u + (unsigned)(j & 15) * 8u;
        *(uint4*)&sA[base] = make_uint4(
            (unsigned)xh | ((unsigned)yh << 16),
            (unsigned)zh | ((unsigned)xl << 16),
            (unsigned)yl | ((unsigned)zl << 16),
            (unsigned)xh | ((unsigned)yh << 16));
        *(uint4*)&sA[base + 128] = make_uint4(
            (unsigned)zh | ((unsigned)wh << 16),
            (unsigned)wl, 0u, 0u);
    }

    const int col = lane & 15;
    const int g   = lane >> 4;
    const int qi  = qbase + w * QPW + col;
    const float qx = x2[qi], qy = x2[N2V + qi], qz = x2[2*N2V + qi];

    unsigned short qxh,qxl,qyh,qyl,qzh,qzl;
    bsplit(-2.0f * qx, qxh, qxl);
    bsplit(-2.0f * qy, qyh, qyl);
    bsplit(-2.0f * qz, qzh, qzl);
    short8 bf = {0,0,0,0,0,0,0,0};
    if (g == 0) {
        bf[0]=(short)qxh; bf[1]=(short)qyh; bf[2]=(short)qzh;
        bf[3]=(short)qxh; bf[4]=(short)qyh; bf[5]=(short)qzh;
        bf[6]=(short)qxl; bf[7]=(short)qyl;
    } else if (g == 1) {
        bf[0]=(short)qzl; bf[1]=(short)0x3F80; bf[2]=(short)0x3F80;  // 1.0 bf16
    }

    const unsigned short* ap = &sA[(unsigned)(((g & 1) * 128) + col * 8)];

    __syncthreads();

    float c0 = FMAXV, c1 = FMAXV, c2 = FMAXV;
    const float4v zc = {0.0f, 0.0f, 0.0f, 0.0f};
    #pragma unroll
    for (int tl = 0; tl < TILES; ++tl) {
        short8 a = *(const short8*)(ap + tl * 256);
        float4v acc = __builtin_amdgcn_mfma_f32_16x16x32_bf16(a, bf, zc, 0, 0, 0);
        float m = fminf(fminf(fminf(acc[0], acc[1]), acc[2]), acc[3]);
        float kf = __uint_as_float((__float_as_uint(m) & TKEYMASK) | (unsigned)tl);
        c2 = __builtin_amdgcn_fmed3f(c1, c2, kf);
        c1 = __builtin_amdgcn_fmed3f(c0, c1, kf);
        c0 = fminf(c0, kf);
    }

    float e0 = FMAXV, e1 = FMAXV, e2 = FMAXV;
    const int g4 = g * 4;
    #pragma unroll
    for (int m = 0; m < 3; ++m) {
        float km = (m == 0) ? c0 : (m == 1) ? c1 : c2;
        int base = ((int)(__float_as_uint(km) & TMASK)) * 16 + g4;
        #pragma unroll
        for (int p = 0; p < 4; ++p) {
            float4 P = sPts[base + p];
            float dx = P.x - qx, dy = P.y - qy, dz = P.z - qz;
            float d  = fmaf(dx, dx, fmaf(dy, dy, dz * dz));
            float pk = __uint_as_float((__float_as_uint(d) & PKEYMASK)
                                       | (unsigned)(base + p));
            e2 = __builtin_amdgcn_fmed3f(e1, e2, pk);
            e1 = __builtin_amdgcn_fmed3f(e0, e1, pk);
            e0 = fminf(e0, pk);
        }
    }

    sCand[w][lane*3 + 0] = e0;
    sCand[w][lane*3 + 1] = e1;
    sCand[w][lane*3 + 2] = e2;

    if (lane < 16) {
        float b0 = FMAXV, b1 = FMAXV, b2 = FMAXV;
        #pragma unroll
        for (int gg = 0; gg < 4; ++gg) {
            #pragma unroll
            for (int m = 0; m < 3; ++m) {
                float pk = sCand[w][(gg*16 + lane)*3 + m];
                b2 = __builtin_amdgcn_fmed3f(b1, b2, pk);
                b1 = __builtin_amdgcn_fmed3f(b0, b1, pk);
                b0 = fminf(b0, pk);
            }
        }
        float2* wq = ws + ((size_t)(b * NOCT + oc) * N2V + qi) * 3;
        wq[0] = make_float2(__uint_as_float(__float_as_uint(b0) & PKEYMASK),
                            __int_as_float(oc * OCT + (int)(__float_as_uint(b0) & PMASK)));
        wq[1] = make_float2(__uint_as_float(__float_as_uint(b1) & PKEYMASK),
                            __int_as_float(oc * OCT + (int)(__float_as_uint(b1) & PMASK)));
        wq[2] = make_float2(__uint_as_float(__float_as_uint(b2) & PKEYMASK),
                            __int_as_float(oc * OCT + (int)(__float_as_uint(b2) & PMASK)));
    }
}

__global__ __launch_bounds__(256)
void knn_merge(const float* __restrict__ xyz2,
               const float* __restrict__ flow1,
               const float2* __restrict__ ws,
               float* __restrict__ out)
{
    const int gid = blockIdx.x * 256 + threadIdx.x;
    const int b   = gid / N2V;
    const int qi  = gid - b * N2V;

    float b0 = FMAXV, b1 = FMAXV, b2 = FMAXV;
    int   j0 = 0, j1 = 0, j2 = 0;
    for (int oc = 0; oc < NOCT; ++oc) {
        const float2* wq = ws + ((size_t)(b * NOCT + oc) * N2V + qi) * 3;
        #pragma unroll
        for (int m = 0; m < 3; ++m) {
            float2 c = wq[m];
            float d = c.x;
            int   j = __float_as_int(c.y);
            if (d < b2) {
                if (d < b1) {
                    b2 = b1; j2 = j1;
                    if (d < b0) { b1 = b0; j1 = j0; b0 = d; j0 = j; }
                    else        { b1 = d;  j1 = j; }
                } else { b2 = d; j2 = j; }
            }
        }
    }

    float d0 = fmaxf(sqrtf(fmaxf(b0, 0.0f)), 1e-10f);
    float d1 = fmaxf(sqrtf(fmaxf(b1, 0.0f)), 1e-10f);
    float d2 = fmaxf(sqrtf(fmaxf(b2, 0.0f)), 1e-10f);
    float i0 = 1.0f / d0, i1 = 1.0f / d1, i2 = 1.0f / d2;
    float wsum = i0 + i1 + i2;
    float w0 = i0 / wsum, w1 = i1 / wsum, w2 = i2 / wsum;

    const float* f1 = flow1 + b * 3 * N1V;
    const float* x2 = xyz2 + b * 3 * N2V;
    float fxo = w0 * f1[j0]         + w1 * f1[j1]         + w2 * f1[j2];
    float fyo = w0 * f1[N1V + j0]   + w1 * f1[N1V + j1]   + w2 * f1[N1V + j2];
    float fzo = w0 * f1[2*N1V + j0] + w1 * f1[2*N1V + j1] + w2 * f1[2*N1V + j2];

    float* ob = out + b * 3 * N2V;
    ob[qi]         = x2[qi]         - fxo;
    ob[N2V + qi]   = x2[N2V + qi]   - fyo;
    ob[2*N2V + qi] = x2[2*N2V + qi] - fzo;
}

extern "C" void kernel_launch(void* const* d_in, const int* in_sizes, int n_in,
                              void* d_out, int out_size, void* d_ws, size_t ws_size,
                              hipStream_t stream)
{
    const float* xyz1  = (const float*)d_in[0];
    const float* xyz2  = (const float*)d_in[1];
    const float* flow1 = (const float*)d_in[2];
    float* out = (float*)d_out;
    const int B = in_sizes[0] / (3 * N1V);

    float2* ws = (float2*)d_ws;   // B * NOCT * N2V * 3 * 8 B = 3.1 MB @ B=2

    dim3 grid(N2V / QPB, NOCT, B);    // (32, 8, B) = 512 blocks
    // ABLATION: replicate part1 4x (idempotent ws writes) to decompose
    // dur = 4*p + m + 5*ovh  vs  R6's  p + m + 2*ovh = 27.8
    knn_part<<<grid, BLOCK, 0, stream>>>(xyz1, xyz2, flow1, ws);
    knn_part<<<grid, BLOCK, 0, stream>>>(xyz1, xyz2, flow1, ws);
    knn_part<<<grid, BLOCK, 0, stream>>>(xyz1, xyz2, flow1, ws);
    knn_part<<<grid, BLOCK, 0, stream>>>(xyz1, xyz2, flow1, ws);

    knn_merge<<<(B * N2V) / 256, 256, 0, stream>>>(xyz2, flow1, ws, out);
}

// Round 13
// 29.520 us; speedup vs baseline: 2.6931x; 2.6931x over previous
//
#include <hip/hip_runtime.h>
#include <math.h>

// ===== R6 scan (byte-identical, 27.8us config) + WIDE merge (only change) =====

#define N1V    8192
#define N2V    8192
#define BLOCK  1024               // 16 waves
#define NW     16
#define NOCT   8                  // N1 split into eighths across blockIdx.y
#define OCT    (N1V / NOCT)       // 1024 points staged per block
#define TILES  (OCT / 16)         // 64 MFMA tiles per scan
#define QPW    16                 // queries per wave (MFMA N dim)
#define QPB    (NW * QPW)         // 256 queries per block
#define TKEYMASK 0xFFFFFFC0u      // tile key: low 6 bits = tile id
#define TMASK    0x3Fu
#define PKEYMASK 0xFFFFFC00u      // point key: low 10 bits = local point idx
#define PMASK    0x3FFu
#define FMAXV  __uint_as_float(0x7F7FFFFFu)

typedef __attribute__((ext_vector_type(8))) short short8;
typedef __attribute__((ext_vector_type(4))) float float4v;

__device__ __forceinline__ void bsplit(float x, unsigned short& h, unsigned short& l) {
    unsigned hb = __float_as_uint(x) & 0xFFFF0000u;
    h = (unsigned short)(hb >> 16);
    float lo = x - __uint_as_float(hb);
    l = (unsigned short)(__float_as_uint(lo) >> 16);
}

__global__ __launch_bounds__(BLOCK, 8)
void knn_part(const float* __restrict__ xyz1,
              const float* __restrict__ xyz2,
              const float* __restrict__ flow1,
              float2* __restrict__ ws)
{
    __shared__ __align__(16) unsigned short sA[TILES * 256]; // 32 KB bf16 A-frags
    __shared__ float4 sPts[OCT];                             // 16 KB exact points
    __shared__ float  sCand[NW][64 * 3];                     // 12 KB packed top-3

    const int b     = blockIdx.z;
    const int oc    = blockIdx.y;
    const int qbase = blockIdx.x * QPB;
    const int t     = threadIdx.x;
    const int lane  = t & 63;
    const int w     = t >> 6;

    const float* x1 = xyz1 + b * 3 * N1V + oc * OCT;
    const float* f1 = flow1 + b * 3 * N1V + oc * OCT;
    const float* x2 = xyz2 + b * 3 * N2V;

    {
        const int j = t;
        float sx = x1[j]           + f1[j];
        float sy = x1[N1V + j]     + f1[N1V + j];
        float sz = x1[2*N1V + j]   + f1[2*N1V + j];
        float wv = fmaf(sx, sx, fmaf(sy, sy, sz * sz));
        sPts[j] = make_float4(sx, sy, sz, wv);
        unsigned short xh,xl,yh,yl,zh,zl,wh,wl;
        bsplit(sx, xh, xl); bsplit(sy, yh, yl);
        bsplit(sz, zh, zl); bsplit(wv, wh, wl);
        unsigned base = (unsigned)(j >> 4) * 256u + (unsigned)(j & 15) * 8u;
        *(uint4*)&sA[base] = make_uint4(
            (unsigned)xh | ((unsigned)yh << 16),
            (unsigned)zh | ((unsigned)xl << 16),
            (unsigned)yl | ((unsigned)zl << 16),
            (unsigned)xh | ((unsigned)yh << 16));
        *(uint4*)&sA[base + 128] = make_uint4(
            (unsigned)zh | ((unsigned)wh << 16),
            (unsigned)wl, 0u, 0u);
    }

    const int col = lane & 15;
    const int g   = lane >> 4;
    const int qi  = qbase + w * QPW + col;
    const float qx = x2[qi], qy = x2[N2V + qi], qz = x2[2*N2V + qi];

    unsigned short qxh,qxl,qyh,qyl,qzh,qzl;
    bsplit(-2.0f * qx, qxh, qxl);
    bsplit(-2.0f * qy, qyh, qyl);
    bsplit(-2.0f * qz, qzh, qzl);
    short8 bf = {0,0,0,0,0,0,0,0};
    if (g == 0) {
        bf[0]=(short)qxh; bf[1]=(short)qyh; bf[2]=(short)qzh;
        bf[3]=(short)qxh; bf[4]=(short)qyh; bf[5]=(short)qzh;
        bf[6]=(short)qxl; bf[7]=(short)qyl;
    } else if (g == 1) {
        bf[0]=(short)qzl; bf[1]=(short)0x3F80; bf[2]=(short)0x3F80;  // 1.0 bf16
    }

    const unsigned short* ap = &sA[(unsigned)(((g & 1) * 128) + col * 8)];

    __syncthreads();

    float c0 = FMAXV, c1 = FMAXV, c2 = FMAXV;
    const float4v zc = {0.0f, 0.0f, 0.0f, 0.0f};
    #pragma unroll
    for (int tl = 0; tl < TILES; ++tl) {
        short8 a = *(const short8*)(ap + tl * 256);
        float4v acc = __builtin_amdgcn_mfma_f32_16x16x32_bf16(a, bf, zc, 0, 0, 0);
        float m = fminf(fminf(fminf(acc[0], acc[1]), acc[2]), acc[3]);
        float kf = __uint_as_float((__float_as_uint(m) & TKEYMASK) | (unsigned)tl);
        c2 = __builtin_amdgcn_fmed3f(c1, c2, kf);
        c1 = __builtin_amdgcn_fmed3f(c0, c1, kf);
        c0 = fminf(c0, kf);
    }

    float e0 = FMAXV, e1 = FMAXV, e2 = FMAXV;
    const int g4 = g * 4;
    #pragma unroll
    for (int m = 0; m < 3; ++m) {
        float km = (m == 0) ? c0 : (m == 1) ? c1 : c2;
        int base = ((int)(__float_as_uint(km) & TMASK)) * 16 + g4;
        #pragma unroll
        for (int p = 0; p < 4; ++p) {
            float4 P = sPts[base + p];
            float dx = P.x - qx, dy = P.y - qy, dz = P.z - qz;
            float d  = fmaf(dx, dx, fmaf(dy, dy, dz * dz));
            float pk = __uint_as_float((__float_as_uint(d) & PKEYMASK)
                                       | (unsigned)(base + p));
            e2 = __builtin_amdgcn_fmed3f(e1, e2, pk);
            e1 = __builtin_amdgcn_fmed3f(e0, e1, pk);
            e0 = fminf(e0, pk);
        }
    }

    sCand[w][lane*3 + 0] = e0;
    sCand[w][lane*3 + 1] = e1;
    sCand[w][lane*3 + 2] = e2;

    if (lane < 16) {
        float b0 = FMAXV, b1 = FMAXV, b2 = FMAXV;
        #pragma unroll
        for (int gg = 0; gg < 4; ++gg) {
            #pragma unroll
            for (int m = 0; m < 3; ++m) {
                float pk = sCand[w][(gg*16 + lane)*3 + m];
                b2 = __builtin_amdgcn_fmed3f(b1, b2, pk);
                b1 = __builtin_amdgcn_fmed3f(b0, b1, pk);
                b0 = fminf(b0, pk);
            }
        }
        float2* wq = ws + ((size_t)(b * NOCT + oc) * N2V + qi) * 3;
        wq[0] = make_float2(__uint_as_float(__float_as_uint(b0) & PKEYMASK),
                            __int_as_float(oc * OCT + (int)(__float_as_uint(b0) & PMASK)));
        wq[1] = make_float2(__uint_as_float(__float_as_uint(b1) & PKEYMASK),
                            __int_as_float(oc * OCT + (int)(__float_as_uint(b1) & PMASK)));
        wq[2] = make_float2(__uint_as_float(__float_as_uint(b2) & PKEYMASK),
                            __int_as_float(oc * OCT + (int)(__float_as_uint(b2) & PMASK)));
    }
}

// ---- merge: 64-thread blocks -> 256 blocks, all CUs active (ONLY change) ---
__global__ __launch_bounds__(64)
void knn_merge(const float* __restrict__ xyz2,
               const float* __restrict__ flow1,
               const float2* __restrict__ ws,
               float* __restrict__ out)
{
    const int gid = blockIdx.x * 64 + threadIdx.x;
    const int b   = gid / N2V;
    const int qi  = gid - b * N2V;

    float b0 = FMAXV, b1 = FMAXV, b2 = FMAXV;
    int   j0 = 0, j1 = 0, j2 = 0;
    for (int oc = 0; oc < NOCT; ++oc) {
        const float2* wq = ws + ((size_t)(b * NOCT + oc) * N2V + qi) * 3;
        #pragma unroll
        for (int m = 0; m < 3; ++m) {
            float2 c = wq[m];
            float d = c.x;
            int   j = __float_as_int(c.y);
            if (d < b2) {
                if (d < b1) {
                    b2 = b1; j2 = j1;
                    if (d < b0) { b1 = b0; j1 = j0; b0 = d; j0 = j; }
                    else        { b1 = d;  j1 = j; }
                } else { b2 = d; j2 = j; }
            }
        }
    }

    float d0 = fmaxf(sqrtf(fmaxf(b0, 0.0f)), 1e-10f);
    float d1 = fmaxf(sqrtf(fmaxf(b1, 0.0f)), 1e-10f);
    float d2 = fmaxf(sqrtf(fmaxf(b2, 0.0f)), 1e-10f);
    float i0 = 1.0f / d0, i1 = 1.0f / d1, i2 = 1.0f / d2;
    float wsum = i0 + i1 + i2;
    float w0 = i0 / wsum, w1 = i1 / wsum, w2 = i2 / wsum;

    const float* f1 = flow1 + b * 3 * N1V;
    const float* x2 = xyz2 + b * 3 * N2V;
    float fxo = w0 * f1[j0]         + w1 * f1[j1]         + w2 * f1[j2];
    float fyo = w0 * f1[N1V + j0]   + w1 * f1[N1V + j1]   + w2 * f1[N1V + j2];
    float fzo = w0 * f1[2*N1V + j0] + w1 * f1[2*N1V + j1] + w2 * f1[2*N1V + j2];

    float* ob = out + b * 3 * N2V;
    ob[qi]         = x2[qi]         - fxo;
    ob[N2V + qi]   = x2[N2V + qi]   - fyo;
    ob[2*N2V + qi] = x2[2*N2V + qi] - fzo;
}

extern "C" void kernel_launch(void* const* d_in, const int* in_sizes, int n_in,
                              void* d_out, int out_size, void* d_ws, size_t ws_size,
                              hipStream_t stream)
{
    const float* xyz1  = (const float*)d_in[0];
    const float* xyz2  = (const float*)d_in[1];
    const float* flow1 = (const float*)d_in[2];
    float* out = (float*)d_out;
    const int B = in_sizes[0] / (3 * N1V);

    float2* ws = (float2*)d_ws;   // B * NOCT * N2V * 3 * 8 B = 3.1 MB @ B=2

    dim3 grid(N2V / QPB, NOCT, B);    // (32, 8, B) = 512 blocks, 2 per CU
    knn_part<<<grid, BLOCK, 0, stream>>>(xyz1, xyz2, flow1, ws);

    knn_merge<<<(B * N2V) / 64, 64, 0, stream>>>(xyz2, flow1, ws, out);
}